// Round 12
// baseline (393.692 us; speedup 1.0000x reference)
//
#include <hip/hip_runtime.h>
#include <hip/hip_fp16.h>

#define DD 128
#define GG 256
#define PP 8          // src ranges: p = src >> 13 (8192 nodes = 2 MB window)
#define CC 16         // edge chunks for partitioned hist/fill
#define CP 64         // edge chunks for src-degree hist
#define DR 16         // dst ranges for hist/fill blocks
#define RSD 3125      // dst range size (16*3125 = 50000)
#define SR 4          // src ranges for deg_out hist
#define SRS 12544

typedef _Float16 half8 __attribute__((ext_vector_type(8)));
typedef float floatx4 __attribute__((ext_vector_type(4)));

__device__ inline uint2 pack_half4(float4 v) {
    __half2 a = __floats2half2_rn(v.x, v.y);
    __half2 b = __floats2half2_rn(v.z, v.w);
    uint2 u;
    u.x = *reinterpret_cast<unsigned int*>(&a);
    u.y = *reinterpret_cast<unsigned int*>(&b);
    return u;
}

// key[e] = dst | (src << 16)   (N < 65536)
__global__ __launch_bounds__(256) void k_key(const int* __restrict__ src, const int* __restrict__ dst,
                                             unsigned int* __restrict__ key, int E) {
    int i = (blockIdx.x * 256 + threadIdx.x) * 4;
    if (i + 3 < E) {
        int4 s4 = *(const int4*)&src[i];
        int4 d4 = *(const int4*)&dst[i];
        uint4 k4;
        k4.x = (unsigned int)d4.x | ((unsigned int)s4.x << 16);
        k4.y = (unsigned int)d4.y | ((unsigned int)s4.y << 16);
        k4.z = (unsigned int)d4.z | ((unsigned int)s4.z << 16);
        k4.w = (unsigned int)d4.w | ((unsigned int)s4.w << 16);
        *(uint4*)&key[i] = k4;
    } else {
        for (int j = 0; j < 4 && i + j < E; ++j)
            key[i + j] = (unsigned int)dst[i + j] | ((unsigned int)src[i + j] << 16);
    }
}

// src-degree histogram from key: grid SR x CP
__global__ __launch_bounds__(256) void k_hist1(const unsigned int* __restrict__ key,
                                               unsigned int* __restrict__ pout,
                                               int E, int N, int RS, int L) {
    __shared__ int h[SRS];
    int r = blockIdx.x / CP;
    int c = blockIdx.x % CP;
    int r0 = r * RS;
    int r1 = min(r0 + RS, N);
    int nb = r1 - r0;
    for (int i = threadIdx.x; i < nb; i += 256) h[i] = 0;
    __syncthreads();
    int e0 = c * L, e1 = min(e0 + L, E);
    for (int e = e0 + threadIdx.x * 4; e < e1; e += 1024) {
        if (e + 3 < e1) {
            uint4 k4 = *(const uint4*)&key[e];
            int s0 = (int)(k4.x >> 16), s1 = (int)(k4.y >> 16);
            int s2 = (int)(k4.z >> 16), s3 = (int)(k4.w >> 16);
            if (s0 >= r0 && s0 < r1) atomicAdd(&h[s0 - r0], 1);
            if (s1 >= r0 && s1 < r1) atomicAdd(&h[s1 - r0], 1);
            if (s2 >= r0 && s2 < r1) atomicAdd(&h[s2 - r0], 1);
            if (s3 >= r0 && s3 < r1) atomicAdd(&h[s3 - r0], 1);
        } else {
            for (int j = 0; j < 4 && e + j < e1; ++j) {
                int s = (int)(key[e + j] >> 16);
                if (s >= r0 && s < r1) atomicAdd(&h[s - r0], 1);
            }
        }
    }
    __syncthreads();
    for (int i = threadIdx.x; i < nb; i += 256)
        pout[(size_t)c * N + r0 + i] = (unsigned int)h[i];
}

// dst-histogram partitioned by src range p: packed dual-uint16 LDS counters.
// grid DR x CC; part16[(c*PP+p)*N + n]
__global__ __launch_bounds__(256) void k_histp(const unsigned int* __restrict__ key,
                                               unsigned short* __restrict__ part16,
                                               int E, int N, int L) {
    __shared__ unsigned int cnt[4 * RSD];  // 50 KB: pairs (2w,2w+1)
    int r = blockIdx.x / CC;
    int c = blockIdx.x % CC;
    int r0 = r * RSD;
    int r1 = min(r0 + RSD, N);
    int nb = r1 - r0;
    for (int i = threadIdx.x; i < 4 * RSD; i += 256) cnt[i] = 0;
    __syncthreads();
    int e0 = c * L, e1 = min(e0 + L, E);
    for (int e = e0 + threadIdx.x * 4; e < e1; e += 1024) {
        if (e + 3 < e1) {
            uint4 k4 = *(const uint4*)&key[e];
            #pragma unroll
            for (int j = 0; j < 4; ++j) {
                unsigned int kk = (j == 0) ? k4.x : (j == 1) ? k4.y : (j == 2) ? k4.z : k4.w;
                int d = (int)(kk & 0xFFFFu);
                if (d >= r0 && d < r1) {
                    int p = (int)(kk >> 29);  // src>>13 == key>>29
                    atomicAdd(&cnt[(p >> 1) * RSD + (d - r0)], (p & 1) ? 65536u : 1u);
                }
            }
        } else {
            for (int j = 0; j < 4 && e + j < e1; ++j) {
                unsigned int kk = key[e + j];
                int d = (int)(kk & 0xFFFFu);
                if (d >= r0 && d < r1) {
                    int p = (int)(kk >> 29);
                    atomicAdd(&cnt[(p >> 1) * RSD + (d - r0)], (p & 1) ? 65536u : 1u);
                }
            }
        }
    }
    __syncthreads();
    for (int i = threadIdx.x; i < nb; i += 256) {
        #pragma unroll
        for (int w = 0; w < 4; ++w) {
            unsigned int v = cnt[w * RSD + i];
            part16[((size_t)c * PP + 2 * w) * N + r0 + i] = (unsigned short)(v & 0xFFFFu);
            part16[((size_t)c * PP + 2 * w + 1) * N + r0 + i] = (unsigned short)(v >> 16);
        }
    }
}

// reduce: norms, deg_in, per-256-chunk block sums
__global__ __launch_bounds__(256) void k_reduce(const unsigned int* __restrict__ pout,
                                                const unsigned short* __restrict__ part16,
                                                float* __restrict__ norm_out, float* __restrict__ norm_in,
                                                int* __restrict__ deg_in, int* __restrict__ bsum,
                                                int N) {
    __shared__ int ws[4];
    int n = blockIdx.x * 256 + threadIdx.x;
    int so = 0, si = 0;
    if (n < N) {
        for (int c = 0; c < CP; ++c) so += (int)pout[(size_t)c * N + n];
        for (int q = 0; q < CC * PP; ++q) si += (int)part16[(size_t)q * N + n];
        norm_out[n] = rsqrtf(fmaxf((float)so, 1.0f));
        norm_in[n] = rsqrtf(fmaxf((float)si, 1.0f));
        deg_in[n] = si;
    }
    int s = si;
    #pragma unroll
    for (int off = 32; off; off >>= 1) s += __shfl_xor(s, off);
    int lane = threadIdx.x & 63, w = threadIdx.x >> 6;
    if (lane == 0) ws[w] = s;
    __syncthreads();
    if (threadIdx.x == 0) bsum[blockIdx.x] = ws[0] + ws[1] + ws[2] + ws[3];
}

__global__ void k_scan_b(int* bsum, int nblk, int* row_ptr, int n) {
    int lane = threadIdx.x;
    int carry = 0;
    for (int base = 0; base < nblk; base += 64) {
        int i = base + lane;
        int v = (i < nblk) ? bsum[i] : 0;
        int s = v;
        #pragma unroll
        for (int off = 1; off < 64; off <<= 1) {
            int u = __shfl_up(s, off);
            if (lane >= off) s += u;
        }
        if (i < nblk) bsum[i] = carry + s - v;
        carry += __shfl(s, 63);
    }
    if (lane == 0) row_ptr[n] = carry;
}

__global__ __launch_bounds__(256) void k_scan_c(const int* __restrict__ deg, const int* __restrict__ bsum,
                                                int* __restrict__ row_ptr, int N) {
    __shared__ int ws[4];
    int t = threadIdx.x;
    int n = blockIdx.x * 256 + t;
    int v = (n < N) ? deg[n] : 0;
    int lane = t & 63, w = t >> 6;
    int incl = v;
    #pragma unroll
    for (int off = 1; off < 64; off <<= 1) {
        int u = __shfl_up(incl, off);
        if (lane >= off) incl += u;
    }
    if (lane == 63) ws[w] = incl;
    __syncthreads();
    int woff = 0;
    for (int j = 0; j < w; ++j) woff += ws[j];
    if (n < N) row_ptr[n] = bsum[blockIdx.x] + woff + incl - v;
}

// base[(c*PP+p)*N+n] = row_ptr[n] + prefix (p-major, then c)
__global__ void k_basep(const unsigned short* __restrict__ part16, const int* __restrict__ row_ptr,
                        int* __restrict__ base, int N) {
    int n = blockIdx.x * blockDim.x + threadIdx.x;
    if (n >= N) return;
    int run = row_ptr[n];
    for (int p = 0; p < PP; ++p) {
        for (int c = 0; c < CC; ++c) {
            size_t idx = ((size_t)c * PP + p) * N + n;
            base[idx] = run;
            run += (int)part16[idx];
        }
    }
}

__global__ void k_gstart(const int* __restrict__ gid, int* g_start, int N, int G) {
    int g = blockIdx.x * blockDim.x + threadIdx.x;
    if (g > G) return;
    int lo = 0, hi = N;
    while (lo < hi) {
        int mid = (lo + hi) >> 1;
        if (gid[mid] < g) lo = mid + 1; else hi = mid;
    }
    g_start[g] = lo;
}

// fill: packed LDS offset counters + per-edge base read (L2-resident window)
__global__ __launch_bounds__(256) void k_fillp(const unsigned int* __restrict__ key,
                                               const int* __restrict__ base, int* __restrict__ col_src,
                                               int E, int N, int L) {
    __shared__ unsigned int cnt[4 * RSD];
    int r = blockIdx.x / CC;
    int c = blockIdx.x % CC;
    int r0 = r * RSD;
    int r1 = min(r0 + RSD, N);
    for (int i = threadIdx.x; i < 4 * RSD; i += 256) cnt[i] = 0;
    __syncthreads();
    int e0 = c * L, e1 = min(e0 + L, E);
    for (int e = e0 + threadIdx.x * 4; e < e1; e += 1024) {
        if (e + 3 < e1) {
            uint4 k4 = *(const uint4*)&key[e];
            #pragma unroll
            for (int j = 0; j < 4; ++j) {
                unsigned int kk = (j == 0) ? k4.x : (j == 1) ? k4.y : (j == 2) ? k4.z : k4.w;
                int d = (int)(kk & 0xFFFFu);
                if (d >= r0 && d < r1) {
                    int s = (int)(kk >> 16);
                    int p = s >> 13;
                    unsigned int o32 = atomicAdd(&cnt[(p >> 1) * RSD + (d - r0)], (p & 1) ? 65536u : 1u);
                    int off = (p & 1) ? (int)(o32 >> 16) : (int)(o32 & 0xFFFFu);
                    col_src[base[((size_t)c * PP + p) * N + d] + off] = s;
                }
            }
        } else {
            for (int j = 0; j < 4 && e + j < e1; ++j) {
                unsigned int kk = key[e + j];
                int d = (int)(kk & 0xFFFFu);
                if (d >= r0 && d < r1) {
                    int s = (int)(kk >> 16);
                    int p = s >> 13;
                    unsigned int o32 = atomicAdd(&cnt[(p >> 1) * RSD + (d - r0)], (p & 1) ? 65536u : 1u);
                    int off = (p & 1) ? (int)(o32 >> 16) : (int)(o32 & 0xFFFFu);
                    col_src[base[((size_t)c * PP + p) * N + d] + off] = s;
                }
            }
        }
    }
}

// W[l] f32 [k][n] -> Wt half [n][k]
__global__ void k_wconv(const float* __restrict__ W, __half* __restrict__ Wt) {
    int i = blockIdx.x * blockDim.x + threadIdx.x;
    if (i >= 3 * 16384) return;
    int l = i >> 14;
    int rem = i & 16383;
    int n = rem >> 7;
    int k = rem & 127;
    Wt[(size_t)l * 16384 + n * 128 + k] = __float2half(W[(size_t)l * 16384 + k * 128 + n]);
}

__global__ void k_scale(const float* __restrict__ h, const float* __restrict__ norm_out,
                        uint2* __restrict__ Xh, int N) {
    int i = blockIdx.x * blockDim.x + threadIdx.x;
    if (i < N * 32) {
        int n = i >> 5;
        float4 v = ((const float4*)h)[i];
        float s = norm_out[n];
        v.x *= s; v.y *= s; v.z *= s; v.w *= s;
        Xh[i] = pack_half4(v);
    }
}

__device__ inline void acc_row(float* acc, uint4 u) {
    const __half2* h = (const __half2*)&u;
    #pragma unroll
    for (int i = 0; i < 4; ++i) {
        float2 f = __half22float2(h[i]);
        acc[2 * i] += f.x;
        acc[2 * i + 1] += f.y;
    }
}

// pull-mode aggregation: 16 lanes/node, uint4 per lane, idx prefetch. Plain loads (nt reverted).
__global__ __launch_bounds__(256, 8) void k_agg(const uint4* __restrict__ Xin, const float* __restrict__ norm_in,
                                                const int* __restrict__ row_ptr, const int* __restrict__ col_src,
                                                uint4* __restrict__ Yh, int N) {
    int t = threadIdx.x;
    int l16 = t & 15;
    int n = blockIdx.x * 16 + (t >> 4);
    if (n >= N) return;
    int beg = row_ptr[n], end = row_ptr[n + 1];
    float acc[8] = {};
    int k = beg;
    bool have = (k + 3 < end);
    int4 s = make_int4(0, 0, 0, 0);
    if (have) s = *(const int4*)&col_src[k];
    while (have) {
        int kn = k + 4;
        bool haven = (kn + 3 < end);
        int4 sn = s;
        if (haven) sn = *(const int4*)&col_src[kn];
        uint4 u0 = Xin[(size_t)s.x * 16 + l16];
        uint4 u1 = Xin[(size_t)s.y * 16 + l16];
        uint4 u2 = Xin[(size_t)s.z * 16 + l16];
        uint4 u3 = Xin[(size_t)s.w * 16 + l16];
        acc_row(acc, u0);
        acc_row(acc, u1);
        acc_row(acc, u2);
        acc_row(acc, u3);
        s = sn; k = kn; have = haven;
    }
    for (; k < end; ++k) {
        uint4 u = Xin[(size_t)col_src[k] * 16 + l16];
        acc_row(acc, u);
    }
    float ni = norm_in[n];
    #pragma unroll
    for (int i = 0; i < 8; ++i) acc[i] *= ni;
    __half2 hp[4];
    #pragma unroll
    for (int i = 0; i < 4; ++i) hp[i] = __floats2half2_rn(acc[2 * i], acc[2 * i + 1]);
    Yh[(size_t)n * 16 + l16] = *(uint4*)hp;
}

// MFMA GEMM: z = relu(Yh[n] @ W + b); outh = half(z * sc) or outf = z.
__global__ __launch_bounds__(256) void k_mm_mfma(const __half* __restrict__ Yh, const __half* __restrict__ Wt,
                                                 const float* __restrict__ bl, const float* __restrict__ scale,
                                                 float* __restrict__ outf, __half* __restrict__ outh, int N) {
    __shared__ _Float16 Ah[64 * 136];
    __shared__ _Float16 Bt[128 * 136];
    int tid = threadIdx.x;
    int n0 = blockIdx.x * 64;

    for (int q = tid; q < 1024; q += 256) {
        int r = q >> 4, c = q & 15;
        int node = n0 + r;
        float4 v = make_float4(0.f, 0.f, 0.f, 0.f);
        if (node < N) v = *(const float4*)&Yh[(size_t)node * 128 + c * 8];
        *(float4*)&Ah[r * 136 + c * 8] = v;
    }
    for (int q = tid; q < 2048; q += 256) {
        int r = q >> 4, c = q & 15;
        *(float4*)&Bt[r * 136 + c * 8] = *(const float4*)&Wt[(size_t)r * 128 + c * 8];
    }
    __syncthreads();

    int wave = tid >> 6;
    int lane = tid & 63;
    int quad = lane >> 4;
    int mrow = lane & 15;
    int m0 = wave * 16;

    half8 af[4];
    #pragma unroll
    for (int kc = 0; kc < 4; ++kc)
        af[kc] = *(const half8*)&Ah[(m0 + mrow) * 136 + kc * 32 + quad * 8];

    floatx4 acc[8];
    #pragma unroll
    for (int ct = 0; ct < 8; ++ct) acc[ct] = (floatx4){0.f, 0.f, 0.f, 0.f};

    #pragma unroll
    for (int ct = 0; ct < 8; ++ct) {
        #pragma unroll
        for (int kc = 0; kc < 4; ++kc) {
            half8 bf = *(const half8*)&Bt[(ct * 16 + mrow) * 136 + kc * 32 + quad * 8];
            acc[ct] = __builtin_amdgcn_mfma_f32_16x16x32_f16(af[kc], bf, acc[ct], 0, 0, 0);
        }
    }

    float sc[4];
    #pragma unroll
    for (int r = 0; r < 4; ++r) {
        int node = n0 + m0 + quad * 4 + r;
        sc[r] = (scale && node < N) ? scale[node] : 1.0f;
    }
    #pragma unroll
    for (int ct = 0; ct < 8; ++ct) {
        int col = ct * 16 + mrow;
        float bias = bl[col];
        #pragma unroll
        for (int r = 0; r < 4; ++r) {
            int node = n0 + m0 + quad * 4 + r;
            if (node < N) {
                float val = fmaxf(acc[ct][r] + bias, 0.f);
                if (outh) outh[(size_t)node * 128 + col] = __float2half(val * sc[r]);
                else outf[(size_t)node * 128 + col] = val;
            }
        }
    }
}

// pooled mean readout from half F
__global__ __launch_bounds__(256) void k_pool(const __half2* __restrict__ Fh, const int* __restrict__ g_start,
                                              float* __restrict__ out) {
    __shared__ float2 red[4][64];
    int g = blockIdx.x;
    int t = threadIdx.x;
    int cp = t & 63;
    int nl = t >> 6;
    int beg = g_start[g], end = g_start[g + 1];
    float2 acc = make_float2(0.f, 0.f);
    for (int n = beg + nl; n < end; n += 4) {
        float2 f = __half22float2(Fh[(size_t)n * 64 + cp]);
        acc.x += f.x;
        acc.y += f.y;
    }
    red[nl][cp] = acc;
    __syncthreads();
    if (nl == 0) {
        float2 a0 = red[0][cp], a1 = red[1][cp], a2 = red[2][cp], a3 = red[3][cp];
        float cnt = fmaxf((float)(end - beg), 1.0f);
        float2 o;
        o.x = (a0.x + a1.x + a2.x + a3.x) / cnt;
        o.y = (a0.y + a1.y + a2.y + a3.y) / cnt;
        *(float2*)&out[(size_t)g * DD + cp * 2] = o;
    }
}

extern "C" void kernel_launch(void* const* d_in, const int* in_sizes, int n_in,
                              void* d_out, int out_size, void* d_ws, size_t ws_size,
                              hipStream_t stream) {
    const float* feats = (const float*)d_in[0];
    const float* W = (const float*)d_in[1];
    const float* b = (const float*)d_in[2];
    const int* src = (const int*)d_in[3];
    const int* dst = (const int*)d_in[4];
    const int* gid = (const int*)d_in[5];
    float* out = (float*)d_out;
    const int N = in_sizes[0] / DD;  // 50000
    const int E = in_sizes[3];       // 800000

    const int Lc = (((E + CC - 1) / CC) + 3) & ~3;  // 50000
    const int Lp = (((E + CP - 1) / CP) + 3) & ~3;  // 12500
    const int SRSZ = (N + SR - 1) / SR;             // 12500

    char* ws = (char*)d_ws;
    size_t off = 0;
    auto take = [&](size_t bytes) {
        char* p = ws + off;
        off = (off + bytes + 255) & ~(size_t)255;
        return p;
    };
    float* norm_out = (float*)take((size_t)N * 4);
    float* norm_in  = (float*)take((size_t)N * 4);
    int*   deg_in   = (int*)take((size_t)N * 4);
    int*   row_ptr  = (int*)take((size_t)(N + 1) * 4);
    int*   col_src  = (int*)take((size_t)E * 4);
    int*   g_start  = (int*)take((size_t)(GG + 1) * 4);
    int*   bsum     = (int*)take((size_t)1024 * 4);
    unsigned int* key = (unsigned int*)take((size_t)E * 4);
    __half* Wth     = (__half*)take((size_t)3 * 16384 * 2);
    uint4* Xh       = (uint4*)take((size_t)N * DD * 2);
    uint4* Yh       = (uint4*)take((size_t)N * DD * 2);
    // union region: pout + part16 + base during preprocessing; Fh afterwards
    size_t pout_b  = ((size_t)CP * N * 4 + 255) & ~(size_t)255;            // 12.8 MB
    size_t part_b  = ((size_t)CC * PP * N * 2 + 255) & ~(size_t)255;       // 12.8 MB
    size_t base_b  = ((size_t)CC * PP * N * 4 + 255) & ~(size_t)255;       // 25.6 MB
    size_t uni_bytes = pout_b + part_b + base_b;
    size_t fh_bytes = (size_t)N * DD * 2;
    char* uni = take(uni_bytes > fh_bytes ? uni_bytes : fh_bytes);
    unsigned int* pout = (unsigned int*)uni;
    unsigned short* part16 = (unsigned short*)(uni + pout_b);
    int* fbase = (int*)(uni + pout_b + part_b);
    __half* Fh = (__half*)uni;  // alias after preprocessing

    const int nblk = (N + 255) / 256;

    k_key<<<(E + 1023) / 1024, 256, 0, stream>>>(src, dst, key, E);
    k_hist1<<<SR * CP, 256, 0, stream>>>(key, pout, E, N, SRSZ, Lp);
    k_histp<<<DR * CC, 256, 0, stream>>>(key, part16, E, N, Lc);
    k_reduce<<<nblk, 256, 0, stream>>>(pout, part16, norm_out, norm_in, deg_in, bsum, N);
    k_gstart<<<1, 512, 0, stream>>>(gid, g_start, N, GG);
    k_wconv<<<(3 * 16384 + 255) / 256, 256, 0, stream>>>(W, Wth);
    k_scan_b<<<1, 64, 0, stream>>>(bsum, nblk, row_ptr, N);
    k_scan_c<<<nblk, 256, 0, stream>>>(deg_in, bsum, row_ptr, N);
    k_basep<<<(N + 255) / 256, 256, 0, stream>>>(part16, row_ptr, fbase, N);
    k_fillp<<<DR * CC, 256, 0, stream>>>(key, fbase, col_src, E, N, Lc);

    k_scale<<<(N * 32 + 255) / 256, 256, 0, stream>>>(feats, norm_out, (uint2*)Xh, N);

    const int agrid = (N + 15) / 16;
    const int mgrid = (N + 63) / 64;
    for (int l = 0; l < 3; ++l) {
        k_agg<<<agrid, 256, 0, stream>>>(Xh, norm_in, row_ptr, col_src, Yh, N);
        const __half* Wtl = Wth + (size_t)l * 16384;
        const float* bl = b + (size_t)l * DD;
        if (l < 2)
            k_mm_mfma<<<mgrid, 256, 0, stream>>>((const __half*)Yh, Wtl, bl, norm_out,
                                                 nullptr, (__half*)Xh, N);
        else
            k_mm_mfma<<<mgrid, 256, 0, stream>>>((const __half*)Yh, Wtl, bl, nullptr,
                                                 nullptr, Fh, N);
    }
    k_pool<<<GG, 256, 0, stream>>>((const __half2*)Fh, g_start, out);
}

// Round 13
// 327.516 us; speedup vs baseline: 1.2021x; 1.2021x over previous
//
#include <hip/hip_runtime.h>
#include <hip/hip_fp16.h>

#define DD 128
#define GG 256
#define RANGES 4
#define RSMAX 12544
#define NCHUNK 32

typedef _Float16 half8 __attribute__((ext_vector_type(8)));
typedef float floatx4 __attribute__((ext_vector_type(4)));

__device__ inline uint2 pack_half4(float4 v) {
    __half2 a = __floats2half2_rn(v.x, v.y);
    __half2 b = __floats2half2_rn(v.z, v.w);
    uint2 u;
    u.x = *reinterpret_cast<unsigned int*>(&a);
    u.y = *reinterpret_cast<unsigned int*>(&b);
    return u;
}

// ---------------- single-index LDS range-partitioned histogram ----------------
// one pass over ONE index array (src or dst); 4 ranges x 12500 nodes, 50 KB LDS.
__global__ __launch_bounds__(256) void k_hist1(const int* __restrict__ idx,
                                               unsigned int* __restrict__ part,
                                               int E, int N, int C, int RS, int L) {
    __shared__ int h[RSMAX];
    int r = blockIdx.x / C;
    int c = blockIdx.x % C;
    int r0 = r * RS;
    int r1 = min(r0 + RS, N);
    int nb = r1 - r0;
    for (int i = threadIdx.x; i < nb; i += 256) h[i] = 0;
    __syncthreads();
    int e0 = c * L, e1 = min(e0 + L, E);
    for (int e = e0 + threadIdx.x * 4; e < e1; e += 1024) {
        if (e + 3 < e1) {
            int4 s4 = *(const int4*)&idx[e];
            if (s4.x >= r0 && s4.x < r1) atomicAdd(&h[s4.x - r0], 1);
            if (s4.y >= r0 && s4.y < r1) atomicAdd(&h[s4.y - r0], 1);
            if (s4.z >= r0 && s4.z < r1) atomicAdd(&h[s4.z - r0], 1);
            if (s4.w >= r0 && s4.w < r1) atomicAdd(&h[s4.w - r0], 1);
        } else {
            for (int j = 0; j < 4 && e + j < e1; ++j) {
                int s = idx[e + j];
                if (s >= r0 && s < r1) atomicAdd(&h[s - r0], 1);
            }
        }
    }
    __syncthreads();
    for (int i = threadIdx.x; i < nb; i += 256)
        part[(size_t)c * N + r0 + i] = (unsigned int)h[i];
}

// reduce partials -> norms, deg_in, and per-256-chunk block sums (fused scan_a)
__global__ __launch_bounds__(256) void k_reduce(const unsigned int* __restrict__ pout,
                                                const unsigned int* __restrict__ pin,
                                                float* __restrict__ norm_out, float* __restrict__ norm_in,
                                                int* __restrict__ deg_in, int* __restrict__ bsum,
                                                int N, int C) {
    __shared__ int ws[4];
    int n = blockIdx.x * 256 + threadIdx.x;
    int so = 0, si = 0;
    if (n < N) {
        for (int c = 0; c < C; ++c) {
            so += (int)pout[(size_t)c * N + n];
            si += (int)pin[(size_t)c * N + n];
        }
        norm_out[n] = rsqrtf(fmaxf((float)so, 1.0f));
        norm_in[n] = rsqrtf(fmaxf((float)si, 1.0f));
        deg_in[n] = si;
    }
    int s = si;
    #pragma unroll
    for (int off = 32; off; off >>= 1) s += __shfl_xor(s, off);
    int lane = threadIdx.x & 63, w = threadIdx.x >> 6;
    if (lane == 0) ws[w] = s;
    __syncthreads();
    if (threadIdx.x == 0) bsum[blockIdx.x] = ws[0] + ws[1] + ws[2] + ws[3];
}

__global__ void k_scan_b(int* bsum, int nblk, int* row_ptr, int n) {
    int lane = threadIdx.x;
    int carry = 0;
    for (int base = 0; base < nblk; base += 64) {
        int i = base + lane;
        int v = (i < nblk) ? bsum[i] : 0;
        int s = v;
        #pragma unroll
        for (int off = 1; off < 64; off <<= 1) {
            int u = __shfl_up(s, off);
            if (lane >= off) s += u;
        }
        if (i < nblk) bsum[i] = carry + s - v;
        carry += __shfl(s, 63);
    }
    if (lane == 0) row_ptr[n] = carry;
}

// exclusive scan over 256-node chunks (matches k_reduce blocks)
__global__ __launch_bounds__(256) void k_scan_c(const int* __restrict__ deg, const int* __restrict__ bsum,
                                                int* __restrict__ row_ptr, int N) {
    __shared__ int ws[4];
    int t = threadIdx.x;
    int n = blockIdx.x * 256 + t;
    int v = (n < N) ? deg[n] : 0;
    int lane = t & 63, w = t >> 6;
    int incl = v;
    #pragma unroll
    for (int off = 1; off < 64; off <<= 1) {
        int u = __shfl_up(incl, off);
        if (lane >= off) incl += u;
    }
    if (lane == 63) ws[w] = incl;
    __syncthreads();
    int woff = 0;
    for (int j = 0; j < w; ++j) woff += ws[j];
    if (n < N) row_ptr[n] = bsum[blockIdx.x] + woff + incl - v;
}

__global__ void k_base(const unsigned int* __restrict__ pin, const int* __restrict__ row_ptr,
                       int* __restrict__ base, int N, int C) {
    int n = blockIdx.x * blockDim.x + threadIdx.x;
    if (n >= N) return;
    int run = row_ptr[n];
    for (int c = 0; c < C; ++c) {
        int h = (int)pin[(size_t)c * N + n];
        base[(size_t)c * N + n] = run;
        run += h;
    }
}

__global__ void k_gstart(const int* __restrict__ gid, int* g_start, int N, int G) {
    int g = blockIdx.x * blockDim.x + threadIdx.x;
    if (g > G) return;
    int lo = 0, hi = N;
    while (lo < hi) {
        int mid = (lo + hi) >> 1;
        if (gid[mid] < g) lo = mid + 1; else hi = mid;
    }
    g_start[g] = lo;
}

// fill CSR: 4 ranges, LDS slot counters seeded from per-chunk base
__global__ __launch_bounds__(256) void k_fill2(const int* __restrict__ src, const int* __restrict__ dst,
                                               const int* __restrict__ base, int* __restrict__ col_src,
                                               int E, int N, int C, int RS, int L) {
    __shared__ int cnt[RSMAX];
    int r = blockIdx.x / C;
    int c = blockIdx.x % C;
    int r0 = r * RS;
    int r1 = min(r0 + RS, N);
    int nb = r1 - r0;
    const int* bc = base + (size_t)c * N;
    for (int i = threadIdx.x; i < nb; i += 256) cnt[i] = bc[r0 + i];
    __syncthreads();
    int e0 = c * L, e1 = min(e0 + L, E);
    for (int e = e0 + threadIdx.x * 4; e < e1; e += 1024) {
        if (e + 3 < e1) {
            int4 s4 = *(const int4*)&src[e];
            int4 d4 = *(const int4*)&dst[e];
            if (d4.x >= r0 && d4.x < r1) { int o = atomicAdd(&cnt[d4.x - r0], 1); col_src[o] = s4.x; }
            if (d4.y >= r0 && d4.y < r1) { int o = atomicAdd(&cnt[d4.y - r0], 1); col_src[o] = s4.y; }
            if (d4.z >= r0 && d4.z < r1) { int o = atomicAdd(&cnt[d4.z - r0], 1); col_src[o] = s4.z; }
            if (d4.w >= r0 && d4.w < r1) { int o = atomicAdd(&cnt[d4.w - r0], 1); col_src[o] = s4.w; }
        } else {
            for (int j = 0; j < 4 && e + j < e1; ++j) {
                int s = src[e + j], d = dst[e + j];
                if (d >= r0 && d < r1) { int o = atomicAdd(&cnt[d - r0], 1); col_src[o] = s; }
            }
        }
    }
}

// W[l] f32 [k][n] -> Wt half [n][k]
__global__ void k_wconv(const float* __restrict__ W, __half* __restrict__ Wt) {
    int i = blockIdx.x * blockDim.x + threadIdx.x;
    if (i >= 3 * 16384) return;
    int l = i >> 14;
    int rem = i & 16383;
    int n = rem >> 7;
    int k = rem & 127;
    Wt[(size_t)l * 16384 + n * 128 + k] = __float2half(W[(size_t)l * 16384 + k * 128 + n]);
}

// pre-scale rows to half
__global__ void k_scale(const float* __restrict__ h, const float* __restrict__ norm_out,
                        uint2* __restrict__ Xh, int N) {
    int i = blockIdx.x * blockDim.x + threadIdx.x;
    if (i < N * 32) {
        int n = i >> 5;
        float4 v = ((const float4*)h)[i];
        float s = norm_out[n];
        v.x *= s; v.y *= s; v.z *= s; v.w *= s;
        Xh[i] = pack_half4(v);
    }
}

__device__ inline void acc_row(float* acc, uint4 u) {
    const __half2* h = (const __half2*)&u;
    #pragma unroll
    for (int i = 0; i < 4; ++i) {
        float2 f = __half22float2(h[i]);
        acc[2 * i] += f.x;
        acc[2 * i + 1] += f.y;
    }
}

// pull-mode aggregation: 16 lanes/node, uint4 per lane, idx prefetch, plain loads.
__global__ __launch_bounds__(256, 8) void k_agg(const uint4* __restrict__ Xin, const float* __restrict__ norm_in,
                                                const int* __restrict__ row_ptr, const int* __restrict__ col_src,
                                                uint4* __restrict__ Yh, int N) {
    int t = threadIdx.x;
    int l16 = t & 15;
    int n = blockIdx.x * 16 + (t >> 4);
    if (n >= N) return;
    int beg = row_ptr[n], end = row_ptr[n + 1];
    float acc[8] = {};
    int k = beg;
    bool have = (k + 3 < end);
    int4 s = make_int4(0, 0, 0, 0);
    if (have) s = *(const int4*)&col_src[k];
    while (have) {
        int kn = k + 4;
        bool haven = (kn + 3 < end);
        int4 sn = s;
        if (haven) sn = *(const int4*)&col_src[kn];
        uint4 u0 = Xin[(size_t)s.x * 16 + l16];
        uint4 u1 = Xin[(size_t)s.y * 16 + l16];
        uint4 u2 = Xin[(size_t)s.z * 16 + l16];
        uint4 u3 = Xin[(size_t)s.w * 16 + l16];
        acc_row(acc, u0);
        acc_row(acc, u1);
        acc_row(acc, u2);
        acc_row(acc, u3);
        s = sn; k = kn; have = haven;
    }
    for (; k < end; ++k) {
        uint4 u = Xin[(size_t)col_src[k] * 16 + l16];
        acc_row(acc, u);
    }
    float ni = norm_in[n];
    #pragma unroll
    for (int i = 0; i < 8; ++i) acc[i] *= ni;
    __half2 hp[4];
    #pragma unroll
    for (int i = 0; i < 4; ++i) hp[i] = __floats2half2_rn(acc[2 * i], acc[2 * i + 1]);
    Yh[(size_t)n * 16 + l16] = *(uint4*)hp;
}

// MFMA GEMM: z = relu(Yh[n] @ W + b); outh = half(z * sc) or outf = z.
__global__ __launch_bounds__(256) void k_mm_mfma(const __half* __restrict__ Yh, const __half* __restrict__ Wt,
                                                 const float* __restrict__ bl, const float* __restrict__ scale,
                                                 float* __restrict__ outf, __half* __restrict__ outh, int N) {
    __shared__ _Float16 Ah[64 * 136];
    __shared__ _Float16 Bt[128 * 136];
    int tid = threadIdx.x;
    int n0 = blockIdx.x * 64;

    for (int q = tid; q < 1024; q += 256) {
        int r = q >> 4, c = q & 15;
        int node = n0 + r;
        float4 v = make_float4(0.f, 0.f, 0.f, 0.f);
        if (node < N) v = *(const float4*)&Yh[(size_t)node * 128 + c * 8];
        *(float4*)&Ah[r * 136 + c * 8] = v;
    }
    for (int q = tid; q < 2048; q += 256) {
        int r = q >> 4, c = q & 15;
        *(float4*)&Bt[r * 136 + c * 8] = *(const float4*)&Wt[(size_t)r * 128 + c * 8];
    }
    __syncthreads();

    int wave = tid >> 6;
    int lane = tid & 63;
    int quad = lane >> 4;
    int mrow = lane & 15;
    int m0 = wave * 16;

    half8 af[4];
    #pragma unroll
    for (int kc = 0; kc < 4; ++kc)
        af[kc] = *(const half8*)&Ah[(m0 + mrow) * 136 + kc * 32 + quad * 8];

    floatx4 acc[8];
    #pragma unroll
    for (int ct = 0; ct < 8; ++ct) acc[ct] = (floatx4){0.f, 0.f, 0.f, 0.f};

    #pragma unroll
    for (int ct = 0; ct < 8; ++ct) {
        #pragma unroll
        for (int kc = 0; kc < 4; ++kc) {
            half8 bf = *(const half8*)&Bt[(ct * 16 + mrow) * 136 + kc * 32 + quad * 8];
            acc[ct] = __builtin_amdgcn_mfma_f32_16x16x32_f16(af[kc], bf, acc[ct], 0, 0, 0);
        }
    }

    float sc[4];
    #pragma unroll
    for (int r = 0; r < 4; ++r) {
        int node = n0 + m0 + quad * 4 + r;
        sc[r] = (scale && node < N) ? scale[node] : 1.0f;
    }
    #pragma unroll
    for (int ct = 0; ct < 8; ++ct) {
        int col = ct * 16 + mrow;
        float bias = bl[col];
        #pragma unroll
        for (int r = 0; r < 4; ++r) {
            int node = n0 + m0 + quad * 4 + r;
            if (node < N) {
                float val = fmaxf(acc[ct][r] + bias, 0.f);
                if (outh) outh[(size_t)node * 128 + col] = __float2half(val * sc[r]);
                else outf[(size_t)node * 128 + col] = val;
            }
        }
    }
}

// pooled mean readout from half F
__global__ __launch_bounds__(256) void k_pool(const __half2* __restrict__ Fh, const int* __restrict__ g_start,
                                              float* __restrict__ out) {
    __shared__ float2 red[4][64];
    int g = blockIdx.x;
    int t = threadIdx.x;
    int cp = t & 63;
    int nl = t >> 6;
    int beg = g_start[g], end = g_start[g + 1];
    float2 acc = make_float2(0.f, 0.f);
    for (int n = beg + nl; n < end; n += 4) {
        float2 f = __half22float2(Fh[(size_t)n * 64 + cp]);
        acc.x += f.x;
        acc.y += f.y;
    }
    red[nl][cp] = acc;
    __syncthreads();
    if (nl == 0) {
        float2 a0 = red[0][cp], a1 = red[1][cp], a2 = red[2][cp], a3 = red[3][cp];
        float cnt = fmaxf((float)(end - beg), 1.0f);
        float2 o;
        o.x = (a0.x + a1.x + a2.x + a3.x) / cnt;
        o.y = (a0.y + a1.y + a2.y + a3.y) / cnt;
        *(float2*)&out[(size_t)g * DD + cp * 2] = o;
    }
}

extern "C" void kernel_launch(void* const* d_in, const int* in_sizes, int n_in,
                              void* d_out, int out_size, void* d_ws, size_t ws_size,
                              hipStream_t stream) {
    const float* feats = (const float*)d_in[0];
    const float* W = (const float*)d_in[1];
    const float* b = (const float*)d_in[2];
    const int* src = (const int*)d_in[3];
    const int* dst = (const int*)d_in[4];
    const int* gid = (const int*)d_in[5];
    float* out = (float*)d_out;
    const int N = in_sizes[0] / DD;  // 50000
    const int E = in_sizes[3];       // 800000

    const int C = NCHUNK;
    const int RS = (N + RANGES - 1) / RANGES;   // 12500 <= RSMAX
    const int L = (((E + C - 1) / C) + 3) & ~3;

    char* ws = (char*)d_ws;
    size_t off = 0;
    auto take = [&](size_t bytes) {
        char* p = ws + off;
        off = (off + bytes + 255) & ~(size_t)255;
        return p;
    };
    float* norm_out = (float*)take((size_t)N * 4);
    float* norm_in  = (float*)take((size_t)N * 4);
    int*   deg_in   = (int*)take((size_t)N * 4);
    int*   row_ptr  = (int*)take((size_t)(N + 1) * 4);
    int*   col_src  = (int*)take((size_t)E * 4);
    int*   g_start  = (int*)take((size_t)(GG + 1) * 4);
    int*   bsum     = (int*)take((size_t)1024 * 4);
    __half* Wth     = (__half*)take((size_t)3 * 16384 * 2);
    uint4* Xh       = (uint4*)take((size_t)N * DD * 2);   // half features
    uint4* Yh       = (uint4*)take((size_t)N * DD * 2);   // half agg output
    // union: pout/pin/fbase during preprocessing; Fh afterwards
    size_t chunk_arr = ((size_t)C * N * 4 + 255) & ~(size_t)255;
    size_t uni_bytes = 3 * chunk_arr;
    size_t fh_bytes = (size_t)N * DD * 2;
    char* uni = take(uni_bytes > fh_bytes ? uni_bytes : fh_bytes);
    unsigned int* pout = (unsigned int*)uni;
    unsigned int* pin  = (unsigned int*)(uni + chunk_arr);
    int* fbase = (int*)(uni + 2 * chunk_arr);
    __half* Fh = (__half*)uni;  // alias: used only after preprocessing completes

    const int nblk = (N + 255) / 256;  // 196 reduce/scan chunks

    k_hist1<<<RANGES * C, 256, 0, stream>>>(src, pout, E, N, C, RS, L);
    k_hist1<<<RANGES * C, 256, 0, stream>>>(dst, pin, E, N, C, RS, L);
    k_reduce<<<nblk, 256, 0, stream>>>(pout, pin, norm_out, norm_in, deg_in, bsum, N, C);
    k_gstart<<<1, 512, 0, stream>>>(gid, g_start, N, GG);
    k_wconv<<<(3 * 16384 + 255) / 256, 256, 0, stream>>>(W, Wth);
    k_scan_b<<<1, 64, 0, stream>>>(bsum, nblk, row_ptr, N);
    k_scan_c<<<nblk, 256, 0, stream>>>(deg_in, bsum, row_ptr, N);
    k_base<<<(N + 255) / 256, 256, 0, stream>>>(pin, row_ptr, fbase, N, C);
    k_fill2<<<RANGES * C, 256, 0, stream>>>(src, dst, fbase, col_src, E, N, C, RS, L);

    k_scale<<<(N * 32 + 255) / 256, 256, 0, stream>>>(feats, norm_out, (uint2*)Xh, N);

    const int agrid = (N + 15) / 16;
    const int mgrid = (N + 63) / 64;
    for (int l = 0; l < 3; ++l) {
        k_agg<<<agrid, 256, 0, stream>>>(Xh, norm_in, row_ptr, col_src, Yh, N);
        const __half* Wtl = Wth + (size_t)l * 16384;
        const float* bl = b + (size_t)l * DD;
        if (l < 2)
            k_mm_mfma<<<mgrid, 256, 0, stream>>>((const __half*)Yh, Wtl, bl, norm_out,
                                                 nullptr, (__half*)Xh, N);
        else
            k_mm_mfma<<<mgrid, 256, 0, stream>>>((const __half*)Yh, Wtl, bl, nullptr,
                                                 nullptr, Fh, N);
    }
    k_pool<<<GG, 256, 0, stream>>>((const __half2*)Fh, g_start, out);
}

// Round 14
// 308.813 us; speedup vs baseline: 1.2749x; 1.0606x over previous
//
#include <hip/hip_runtime.h>
#include <hip/hip_fp16.h>

#define DD 128
#define GG 256
#define RANGES 8
#define RSMAX 6400
#define NCHUNK 32

typedef _Float16 half8 __attribute__((ext_vector_type(8)));
typedef float floatx4 __attribute__((ext_vector_type(4)));

__device__ inline uint2 pack_half4(float4 v) {
    __half2 a = __floats2half2_rn(v.x, v.y);
    __half2 b = __floats2half2_rn(v.z, v.w);
    uint2 u;
    u.x = *reinterpret_cast<unsigned int*>(&a);
    u.y = *reinterpret_cast<unsigned int*>(&b);
    return u;
}

// key[e] = src | (dst << 16)   (N < 65536)
__global__ __launch_bounds__(256) void k_key(const int* __restrict__ src, const int* __restrict__ dst,
                                             unsigned int* __restrict__ key, int E) {
    int i = (blockIdx.x * 256 + threadIdx.x) * 4;
    if (i + 3 < E) {
        int4 s4 = *(const int4*)&src[i];
        int4 d4 = *(const int4*)&dst[i];
        uint4 k4;
        k4.x = (unsigned int)s4.x | ((unsigned int)d4.x << 16);
        k4.y = (unsigned int)s4.y | ((unsigned int)d4.y << 16);
        k4.z = (unsigned int)s4.z | ((unsigned int)d4.z << 16);
        k4.w = (unsigned int)s4.w | ((unsigned int)d4.w << 16);
        *(uint4*)&key[i] = k4;
    } else {
        for (int j = 0; j < 4 && i + j < E; ++j)
            key[i + j] = (unsigned int)src[i + j] | ((unsigned int)dst[i + j] << 16);
    }
}

// ---------------- LDS range-partitioned histogram from key, packed partials ----------------
// pk[c][n] = deg_out_partial | (deg_in_partial << 16); grid RANGES x NCHUNK (256 blocks).
__global__ __launch_bounds__(256) void k_hist2(const unsigned int* __restrict__ key,
                                               unsigned int* __restrict__ pk,
                                               int E, int N, int C, int RS, int L) {
    __shared__ int ho[RSMAX];
    __shared__ int hi[RSMAX];
    int r = blockIdx.x / C;
    int c = blockIdx.x % C;
    int r0 = r * RS;
    int r1 = min(r0 + RS, N);
    int nb = r1 - r0;
    for (int i = threadIdx.x; i < nb; i += 256) { ho[i] = 0; hi[i] = 0; }
    __syncthreads();
    int e0 = c * L, e1 = min(e0 + L, E);
    for (int e = e0 + threadIdx.x * 4; e < e1; e += 1024) {
        if (e + 3 < e1) {
            uint4 k4 = *(const uint4*)&key[e];
            #pragma unroll
            for (int j = 0; j < 4; ++j) {
                unsigned int kk = (j == 0) ? k4.x : (j == 1) ? k4.y : (j == 2) ? k4.z : k4.w;
                int s = (int)(kk & 0xFFFFu);
                int d = (int)(kk >> 16);
                if (s >= r0 && s < r1) atomicAdd(&ho[s - r0], 1);
                if (d >= r0 && d < r1) atomicAdd(&hi[d - r0], 1);
            }
        } else {
            for (int j = 0; j < 4 && e + j < e1; ++j) {
                unsigned int kk = key[e + j];
                int s = (int)(kk & 0xFFFFu);
                int d = (int)(kk >> 16);
                if (s >= r0 && s < r1) atomicAdd(&ho[s - r0], 1);
                if (d >= r0 && d < r1) atomicAdd(&hi[d - r0], 1);
            }
        }
    }
    __syncthreads();
    for (int i = threadIdx.x; i < nb; i += 256)
        pk[(size_t)c * N + r0 + i] = (unsigned int)ho[i] | ((unsigned int)hi[i] << 16);
}

// reduce packed partials -> norms, deg_in, and per-256-chunk block sums (fused scan_a)
__global__ __launch_bounds__(256) void k_reduce(const unsigned int* __restrict__ pk,
                                                float* __restrict__ norm_out, float* __restrict__ norm_in,
                                                int* __restrict__ deg_in, int* __restrict__ bsum,
                                                int N, int C) {
    __shared__ int ws[4];
    int n = blockIdx.x * 256 + threadIdx.x;
    int so = 0, si = 0;
    if (n < N) {
        for (int c = 0; c < C; ++c) {
            unsigned int v = pk[(size_t)c * N + n];
            so += (int)(v & 0xFFFFu);
            si += (int)(v >> 16);
        }
        norm_out[n] = rsqrtf(fmaxf((float)so, 1.0f));
        norm_in[n] = rsqrtf(fmaxf((float)si, 1.0f));
        deg_in[n] = si;
    }
    int s = si;
    #pragma unroll
    for (int off = 32; off; off >>= 1) s += __shfl_xor(s, off);
    int lane = threadIdx.x & 63, w = threadIdx.x >> 6;
    if (lane == 0) ws[w] = s;
    __syncthreads();
    if (threadIdx.x == 0) bsum[blockIdx.x] = ws[0] + ws[1] + ws[2] + ws[3];
}

// multi-role kernel: block 0 = scan_b over bsum; blocks 1-2 = gstart; blocks 3..194 = wconv;
// blocks 195.. = scale (feats * norm_out -> half Xh). All deps satisfied post-reduce.
__global__ __launch_bounds__(256) void k_misc(int* bsum, int nblk, int* row_ptr, int N,
                                              const int* __restrict__ gid, int* g_start, int G,
                                              const float* __restrict__ W, __half* __restrict__ Wt,
                                              const float* __restrict__ feats,
                                              const float* __restrict__ norm_out,
                                              uint2* __restrict__ Xh) {
    int blk = blockIdx.x;
    int tid = threadIdx.x;
    if (blk == 0) {
        if (tid < 64) {
            int lane = tid;
            int carry = 0;
            for (int base = 0; base < nblk; base += 64) {
                int i = base + lane;
                int v = (i < nblk) ? bsum[i] : 0;
                int s = v;
                #pragma unroll
                for (int off = 1; off < 64; off <<= 1) {
                    int u = __shfl_up(s, off);
                    if (lane >= off) s += u;
                }
                if (i < nblk) bsum[i] = carry + s - v;
                carry += __shfl(s, 63);
            }
            if (lane == 0) row_ptr[N] = carry;
        }
    } else if (blk <= 2) {
        int g = (blk - 1) * 256 + tid;
        if (g <= G) {
            int lo = 0, hi = N;
            while (lo < hi) {
                int mid = (lo + hi) >> 1;
                if (gid[mid] < g) lo = mid + 1; else hi = mid;
            }
            g_start[g] = lo;
        }
    } else if (blk <= 194) {
        int i = (blk - 3) * 256 + tid;
        if (i < 3 * 16384) {
            int l = i >> 14;
            int rem = i & 16383;
            int n = rem >> 7;
            int k = rem & 127;
            Wt[(size_t)l * 16384 + n * 128 + k] = __float2half(W[(size_t)l * 16384 + k * 128 + n]);
        }
    } else {
        int i = (blk - 195) * 256 + tid;
        if (i < N * 32) {
            int n = i >> 5;
            float4 v = ((const float4*)feats)[i];
            float s = norm_out[n];
            v.x *= s; v.y *= s; v.z *= s; v.w *= s;
            Xh[i] = pack_half4(v);
        }
    }
}

// exclusive scan over 256-node chunks (matches k_reduce blocks) + fused per-chunk fill base
__global__ __launch_bounds__(256) void k_scan_cb(const int* __restrict__ deg, const int* __restrict__ bsum,
                                                 const unsigned int* __restrict__ pk,
                                                 int* __restrict__ row_ptr, int* __restrict__ fbase,
                                                 int N, int C) {
    __shared__ int ws[4];
    int t = threadIdx.x;
    int n = blockIdx.x * 256 + t;
    int v = (n < N) ? deg[n] : 0;
    int lane = t & 63, w = t >> 6;
    int incl = v;
    #pragma unroll
    for (int off = 1; off < 64; off <<= 1) {
        int u = __shfl_up(incl, off);
        if (lane >= off) incl += u;
    }
    if (lane == 63) ws[w] = incl;
    __syncthreads();
    int woff = 0;
    for (int j = 0; j < w; ++j) woff += ws[j];
    if (n < N) {
        int run = bsum[blockIdx.x] + woff + incl - v;
        row_ptr[n] = run;
        for (int c = 0; c < C; ++c) {
            int h = (int)(pk[(size_t)c * N + n] >> 16);
            fbase[(size_t)c * N + n] = run;
            run += h;
        }
    }
}

// fill CSR from key: LDS slot counters seeded from per-chunk base
__global__ __launch_bounds__(256) void k_fill2(const unsigned int* __restrict__ key,
                                               const int* __restrict__ base, int* __restrict__ col_src,
                                               int E, int N, int C, int RS, int L) {
    __shared__ int cnt[RSMAX];
    int r = blockIdx.x / C;
    int c = blockIdx.x % C;
    int r0 = r * RS;
    int r1 = min(r0 + RS, N);
    int nb = r1 - r0;
    const int* bc = base + (size_t)c * N;
    for (int i = threadIdx.x; i < nb; i += 256) cnt[i] = bc[r0 + i];
    __syncthreads();
    int e0 = c * L, e1 = min(e0 + L, E);
    for (int e = e0 + threadIdx.x * 4; e < e1; e += 1024) {
        if (e + 3 < e1) {
            uint4 k4 = *(const uint4*)&key[e];
            #pragma unroll
            for (int j = 0; j < 4; ++j) {
                unsigned int kk = (j == 0) ? k4.x : (j == 1) ? k4.y : (j == 2) ? k4.z : k4.w;
                int s = (int)(kk & 0xFFFFu);
                int d = (int)(kk >> 16);
                if (d >= r0 && d < r1) { int o = atomicAdd(&cnt[d - r0], 1); col_src[o] = s; }
            }
        } else {
            for (int j = 0; j < 4 && e + j < e1; ++j) {
                unsigned int kk = key[e + j];
                int s = (int)(kk & 0xFFFFu);
                int d = (int)(kk >> 16);
                if (d >= r0 && d < r1) { int o = atomicAdd(&cnt[d - r0], 1); col_src[o] = s; }
            }
        }
    }
}

__device__ inline void acc_row(float* acc, uint4 u) {
    const __half2* h = (const __half2*)&u;
    #pragma unroll
    for (int i = 0; i < 4; ++i) {
        float2 f = __half22float2(h[i]);
        acc[2 * i] += f.x;
        acc[2 * i + 1] += f.y;
    }
}

// pull-mode aggregation: 16 lanes/node, uint4 per lane, idx prefetch, plain loads.
__global__ __launch_bounds__(256, 8) void k_agg(const uint4* __restrict__ Xin, const float* __restrict__ norm_in,
                                                const int* __restrict__ row_ptr, const int* __restrict__ col_src,
                                                uint4* __restrict__ Yh, int N) {
    int t = threadIdx.x;
    int l16 = t & 15;
    int n = blockIdx.x * 16 + (t >> 4);
    if (n >= N) return;
    int beg = row_ptr[n], end = row_ptr[n + 1];
    float acc[8] = {};
    int k = beg;
    bool have = (k + 3 < end);
    int4 s = make_int4(0, 0, 0, 0);
    if (have) s = *(const int4*)&col_src[k];
    while (have) {
        int kn = k + 4;
        bool haven = (kn + 3 < end);
        int4 sn = s;
        if (haven) sn = *(const int4*)&col_src[kn];
        uint4 u0 = Xin[(size_t)s.x * 16 + l16];
        uint4 u1 = Xin[(size_t)s.y * 16 + l16];
        uint4 u2 = Xin[(size_t)s.z * 16 + l16];
        uint4 u3 = Xin[(size_t)s.w * 16 + l16];
        acc_row(acc, u0);
        acc_row(acc, u1);
        acc_row(acc, u2);
        acc_row(acc, u3);
        s = sn; k = kn; have = haven;
    }
    for (; k < end; ++k) {
        uint4 u = Xin[(size_t)col_src[k] * 16 + l16];
        acc_row(acc, u);
    }
    float ni = norm_in[n];
    #pragma unroll
    for (int i = 0; i < 8; ++i) acc[i] *= ni;
    __half2 hp[4];
    #pragma unroll
    for (int i = 0; i < 4; ++i) hp[i] = __floats2half2_rn(acc[2 * i], acc[2 * i + 1]);
    Yh[(size_t)n * 16 + l16] = *(uint4*)hp;
}

// MFMA GEMM: z = relu(Yh[n] @ W + b); outh = half(z * sc) or outf = z.
__global__ __launch_bounds__(256) void k_mm_mfma(const __half* __restrict__ Yh, const __half* __restrict__ Wt,
                                                 const float* __restrict__ bl, const float* __restrict__ scale,
                                                 float* __restrict__ outf, __half* __restrict__ outh, int N) {
    __shared__ _Float16 Ah[64 * 136];
    __shared__ _Float16 Bt[128 * 136];
    int tid = threadIdx.x;
    int n0 = blockIdx.x * 64;

    for (int q = tid; q < 1024; q += 256) {
        int r = q >> 4, c = q & 15;
        int node = n0 + r;
        float4 v = make_float4(0.f, 0.f, 0.f, 0.f);
        if (node < N) v = *(const float4*)&Yh[(size_t)node * 128 + c * 8];
        *(float4*)&Ah[r * 136 + c * 8] = v;
    }
    for (int q = tid; q < 2048; q += 256) {
        int r = q >> 4, c = q & 15;
        *(float4*)&Bt[r * 136 + c * 8] = *(const float4*)&Wt[(size_t)r * 128 + c * 8];
    }
    __syncthreads();

    int wave = tid >> 6;
    int lane = tid & 63;
    int quad = lane >> 4;
    int mrow = lane & 15;
    int m0 = wave * 16;

    half8 af[4];
    #pragma unroll
    for (int kc = 0; kc < 4; ++kc)
        af[kc] = *(const half8*)&Ah[(m0 + mrow) * 136 + kc * 32 + quad * 8];

    floatx4 acc[8];
    #pragma unroll
    for (int ct = 0; ct < 8; ++ct) acc[ct] = (floatx4){0.f, 0.f, 0.f, 0.f};

    #pragma unroll
    for (int ct = 0; ct < 8; ++ct) {
        #pragma unroll
        for (int kc = 0; kc < 4; ++kc) {
            half8 bf = *(const half8*)&Bt[(ct * 16 + mrow) * 136 + kc * 32 + quad * 8];
            acc[ct] = __builtin_amdgcn_mfma_f32_16x16x32_f16(af[kc], bf, acc[ct], 0, 0, 0);
        }
    }

    float sc[4];
    #pragma unroll
    for (int r = 0; r < 4; ++r) {
        int node = n0 + m0 + quad * 4 + r;
        sc[r] = (scale && node < N) ? scale[node] : 1.0f;
    }
    #pragma unroll
    for (int ct = 0; ct < 8; ++ct) {
        int col = ct * 16 + mrow;
        float bias = bl[col];
        #pragma unroll
        for (int r = 0; r < 4; ++r) {
            int node = n0 + m0 + quad * 4 + r;
            if (node < N) {
                float val = fmaxf(acc[ct][r] + bias, 0.f);
                if (outh) outh[(size_t)node * 128 + col] = __float2half(val * sc[r]);
                else outf[(size_t)node * 128 + col] = val;
            }
        }
    }
}

// pooled mean readout from half F: 4 nodes in flight, 64 col-pairs, LDS reduce.
__global__ __launch_bounds__(256) void k_pool(const __half2* __restrict__ Fh, const int* __restrict__ g_start,
                                              float* __restrict__ out) {
    __shared__ float2 red[4][64];
    int g = blockIdx.x;
    int t = threadIdx.x;
    int cp = t & 63;
    int nl = t >> 6;
    int beg = g_start[g], end = g_start[g + 1];
    float2 acc = make_float2(0.f, 0.f);
    for (int n = beg + nl; n < end; n += 4) {
        float2 f = __half22float2(Fh[(size_t)n * 64 + cp]);
        acc.x += f.x;
        acc.y += f.y;
    }
    red[nl][cp] = acc;
    __syncthreads();
    if (nl == 0) {
        float2 a0 = red[0][cp], a1 = red[1][cp], a2 = red[2][cp], a3 = red[3][cp];
        float cnt = fmaxf((float)(end - beg), 1.0f);
        float2 o;
        o.x = (a0.x + a1.x + a2.x + a3.x) / cnt;
        o.y = (a0.y + a1.y + a2.y + a3.y) / cnt;
        *(float2*)&out[(size_t)g * DD + cp * 2] = o;
    }
}

extern "C" void kernel_launch(void* const* d_in, const int* in_sizes, int n_in,
                              void* d_out, int out_size, void* d_ws, size_t ws_size,
                              hipStream_t stream) {
    const float* feats = (const float*)d_in[0];
    const float* W = (const float*)d_in[1];
    const float* b = (const float*)d_in[2];
    const int* src = (const int*)d_in[3];
    const int* dst = (const int*)d_in[4];
    const int* gid = (const int*)d_in[5];
    float* out = (float*)d_out;
    const int N = in_sizes[0] / DD;  // 50000
    const int E = in_sizes[3];       // 800000

    const int C = NCHUNK;
    const int RS = (N + RANGES - 1) / RANGES;   // 6250 <= RSMAX
    const int L = (((E + C - 1) / C) + 3) & ~3;

    char* ws = (char*)d_ws;
    size_t off = 0;
    auto take = [&](size_t bytes) {
        char* p = ws + off;
        off = (off + bytes + 255) & ~(size_t)255;
        return p;
    };
    float* norm_out = (float*)take((size_t)N * 4);
    float* norm_in  = (float*)take((size_t)N * 4);
    int*   deg_in   = (int*)take((size_t)N * 4);
    int*   row_ptr  = (int*)take((size_t)(N + 1) * 4);
    int*   col_src  = (int*)take((size_t)E * 4);
    int*   g_start  = (int*)take((size_t)(GG + 1) * 4);
    int*   bsum     = (int*)take((size_t)1024 * 4);
    unsigned int* key = (unsigned int*)take((size_t)E * 4);
    __half* Wth     = (__half*)take((size_t)3 * 16384 * 2);
    uint4* Xh       = (uint4*)take((size_t)N * DD * 2);   // half features
    uint4* Yh       = (uint4*)take((size_t)N * DD * 2);   // half agg output
    // union: pk + fbase during preprocessing; Fh (half final layer) afterwards
    size_t chunk_arr = ((size_t)C * N * 4 + 255) & ~(size_t)255;
    size_t uni_bytes = 2 * chunk_arr;
    size_t fh_bytes = (size_t)N * DD * 2;
    char* uni = take(uni_bytes > fh_bytes ? uni_bytes : fh_bytes);
    unsigned int* pk = (unsigned int*)uni;
    int* fbase = (int*)(uni + chunk_arr);
    __half* Fh = (__half*)uni;  // alias: used only after preprocessing completes

    const int nblk = (N + 255) / 256;  // 196 reduce/scan chunks
    const int mgrid_misc = 195 + (N * 32 + 255) / 256;

    k_key<<<(E + 1023) / 1024, 256, 0, stream>>>(src, dst, key, E);
    k_hist2<<<RANGES * C, 256, 0, stream>>>(key, pk, E, N, C, RS, L);
    k_reduce<<<nblk, 256, 0, stream>>>(pk, norm_out, norm_in, deg_in, bsum, N, C);
    k_misc<<<mgrid_misc, 256, 0, stream>>>(bsum, nblk, row_ptr, N, gid, g_start, GG,
                                           W, Wth, feats, norm_out, (uint2*)Xh);
    k_scan_cb<<<nblk, 256, 0, stream>>>(deg_in, bsum, pk, row_ptr, fbase, N, C);
    k_fill2<<<RANGES * C, 256, 0, stream>>>(key, fbase, col_src, E, N, C, RS, L);

    const int agrid = (N + 15) / 16;
    const int mgrid = (N + 63) / 64;
    for (int l = 0; l < 3; ++l) {
        k_agg<<<agrid, 256, 0, stream>>>(Xh, norm_in, row_ptr, col_src, Yh, N);
        const __half* Wtl = Wth + (size_t)l * 16384;
        const float* bl = b + (size_t)l * DD;
        if (l < 2)
            k_mm_mfma<<<mgrid, 256, 0, stream>>>((const __half*)Yh, Wtl, bl, norm_out,
                                                 nullptr, (__half*)Xh, N);
        else
            k_mm_mfma<<<mgrid, 256, 0, stream>>>((const __half*)Yh, Wtl, bl, nullptr,
                                                 nullptr, Fh, N);
    }
    k_pool<<<GG, 256, 0, stream>>>((const __half2*)Fh, g_start, out);
}

// Round 15
// 302.765 us; speedup vs baseline: 1.3003x; 1.0200x over previous
//
#include <hip/hip_runtime.h>
#include <hip/hip_fp16.h>

#define DD 128
#define GG 256
#define RANGES 4
#define RSMAX 12544
#define NCHUNK 64

typedef _Float16 half8 __attribute__((ext_vector_type(8)));
typedef float floatx4 __attribute__((ext_vector_type(4)));

__device__ inline uint2 pack_half4(float4 v) {
    __half2 a = __floats2half2_rn(v.x, v.y);
    __half2 b = __floats2half2_rn(v.z, v.w);
    uint2 u;
    u.x = *reinterpret_cast<unsigned int*>(&a);
    u.y = *reinterpret_cast<unsigned int*>(&b);
    return u;
}

// key[e] = src | (dst << 16)   (N < 65536)
__global__ __launch_bounds__(256) void k_key(const int* __restrict__ src, const int* __restrict__ dst,
                                             unsigned int* __restrict__ key, int E) {
    int i = (blockIdx.x * 256 + threadIdx.x) * 4;
    if (i + 3 < E) {
        int4 s4 = *(const int4*)&src[i];
        int4 d4 = *(const int4*)&dst[i];
        uint4 k4;
        k4.x = (unsigned int)s4.x | ((unsigned int)d4.x << 16);
        k4.y = (unsigned int)s4.y | ((unsigned int)d4.y << 16);
        k4.z = (unsigned int)s4.z | ((unsigned int)d4.z << 16);
        k4.w = (unsigned int)s4.w | ((unsigned int)d4.w << 16);
        *(uint4*)&key[i] = k4;
    } else {
        for (int j = 0; j < 4 && i + j < E; ++j)
            key[i + j] = (unsigned int)src[i + j] | ((unsigned int)dst[i + j] << 16);
    }
}

// ---------------- packed-u16 LDS histogram: h[n] = deg_out | deg_in<<16 ----------------
// grid = RANGES(4) x NCHUNK(64) = 256 blocks, 50 KB LDS each.
__global__ __launch_bounds__(256) void k_hist2(const unsigned int* __restrict__ key,
                                               unsigned int* __restrict__ pk,
                                               int E, int N, int C, int RS, int L) {
    __shared__ unsigned int h[RSMAX];
    int r = blockIdx.x / C;
    int c = blockIdx.x % C;
    int r0 = r * RS;
    int r1 = min(r0 + RS, N);
    int nb = r1 - r0;
    for (int i = threadIdx.x; i < nb; i += 256) h[i] = 0;
    __syncthreads();
    int e0 = c * L, e1 = min(e0 + L, E);
    for (int e = e0 + threadIdx.x * 4; e < e1; e += 1024) {
        if (e + 3 < e1) {
            uint4 k4 = *(const uint4*)&key[e];
            #pragma unroll
            for (int j = 0; j < 4; ++j) {
                unsigned int kk = (j == 0) ? k4.x : (j == 1) ? k4.y : (j == 2) ? k4.z : k4.w;
                int s = (int)(kk & 0xFFFFu);
                int d = (int)(kk >> 16);
                if (s >= r0 && s < r1) atomicAdd(&h[s - r0], 1u);
                if (d >= r0 && d < r1) atomicAdd(&h[d - r0], 65536u);
            }
        } else {
            for (int j = 0; j < 4 && e + j < e1; ++j) {
                unsigned int kk = key[e + j];
                int s = (int)(kk & 0xFFFFu);
                int d = (int)(kk >> 16);
                if (s >= r0 && s < r1) atomicAdd(&h[s - r0], 1u);
                if (d >= r0 && d < r1) atomicAdd(&h[d - r0], 65536u);
            }
        }
    }
    __syncthreads();
    for (int i = threadIdx.x; i < nb; i += 256)
        pk[(size_t)c * N + r0 + i] = h[i];
}

// reduce packed partials -> norms, deg_in, and per-256-chunk block sums (fused scan_a)
__global__ __launch_bounds__(256) void k_reduce(const unsigned int* __restrict__ pk,
                                                float* __restrict__ norm_out, float* __restrict__ norm_in,
                                                int* __restrict__ deg_in, int* __restrict__ bsum,
                                                int N, int C) {
    __shared__ int ws[4];
    int n = blockIdx.x * 256 + threadIdx.x;
    int so = 0, si = 0;
    if (n < N) {
        for (int c = 0; c < C; ++c) {
            unsigned int v = pk[(size_t)c * N + n];
            so += (int)(v & 0xFFFFu);
            si += (int)(v >> 16);
        }
        norm_out[n] = rsqrtf(fmaxf((float)so, 1.0f));
        norm_in[n] = rsqrtf(fmaxf((float)si, 1.0f));
        deg_in[n] = si;
    }
    int s = si;
    #pragma unroll
    for (int off = 32; off; off >>= 1) s += __shfl_xor(s, off);
    int lane = threadIdx.x & 63, w = threadIdx.x >> 6;
    if (lane == 0) ws[w] = s;
    __syncthreads();
    if (threadIdx.x == 0) bsum[blockIdx.x] = ws[0] + ws[1] + ws[2] + ws[3];
}

// multi-role kernel: block 0 = scan_b over bsum; blocks 1-2 = gstart; blocks 3..194 = wconv;
// blocks 195.. = scale (feats * norm_out -> half Xh).
__global__ __launch_bounds__(256) void k_misc(int* bsum, int nblk, int* row_ptr, int N,
                                              const int* __restrict__ gid, int* g_start, int G,
                                              const float* __restrict__ W, __half* __restrict__ Wt,
                                              const float* __restrict__ feats,
                                              const float* __restrict__ norm_out,
                                              uint2* __restrict__ Xh) {
    int blk = blockIdx.x;
    int tid = threadIdx.x;
    if (blk == 0) {
        if (tid < 64) {
            int lane = tid;
            int carry = 0;
            for (int base = 0; base < nblk; base += 64) {
                int i = base + lane;
                int v = (i < nblk) ? bsum[i] : 0;
                int s = v;
                #pragma unroll
                for (int off = 1; off < 64; off <<= 1) {
                    int u = __shfl_up(s, off);
                    if (lane >= off) s += u;
                }
                if (i < nblk) bsum[i] = carry + s - v;
                carry += __shfl(s, 63);
            }
            if (lane == 0) row_ptr[N] = carry;
        }
    } else if (blk <= 2) {
        int g = (blk - 1) * 256 + tid;
        if (g <= G) {
            int lo = 0, hi = N;
            while (lo < hi) {
                int mid = (lo + hi) >> 1;
                if (gid[mid] < g) lo = mid + 1; else hi = mid;
            }
            g_start[g] = lo;
        }
    } else if (blk <= 194) {
        int i = (blk - 3) * 256 + tid;
        if (i < 3 * 16384) {
            int l = i >> 14;
            int rem = i & 16383;
            int n = rem >> 7;
            int k = rem & 127;
            Wt[(size_t)l * 16384 + n * 128 + k] = __float2half(W[(size_t)l * 16384 + k * 128 + n]);
        }
    } else {
        int i = (blk - 195) * 256 + tid;
        if (i < N * 32) {
            int n = i >> 5;
            float4 v = ((const float4*)feats)[i];
            float s = norm_out[n];
            v.x *= s; v.y *= s; v.z *= s; v.w *= s;
            Xh[i] = pack_half4(v);
        }
    }
}

// exclusive scan over 256-node chunks + fused per-chunk fill base
__global__ __launch_bounds__(256) void k_scan_cb(const int* __restrict__ deg, const int* __restrict__ bsum,
                                                 const unsigned int* __restrict__ pk,
                                                 int* __restrict__ row_ptr, int* __restrict__ fbase,
                                                 int N, int C) {
    __shared__ int ws[4];
    int t = threadIdx.x;
    int n = blockIdx.x * 256 + t;
    int v = (n < N) ? deg[n] : 0;
    int lane = t & 63, w = t >> 6;
    int incl = v;
    #pragma unroll
    for (int off = 1; off < 64; off <<= 1) {
        int u = __shfl_up(incl, off);
        if (lane >= off) incl += u;
    }
    if (lane == 63) ws[w] = incl;
    __syncthreads();
    int woff = 0;
    for (int j = 0; j < w; ++j) woff += ws[j];
    if (n < N) {
        int run = bsum[blockIdx.x] + woff + incl - v;
        row_ptr[n] = run;
        for (int c = 0; c < C; ++c) {
            int h = (int)(pk[(size_t)c * N + n] >> 16);
            fbase[(size_t)c * N + n] = run;
            run += h;
        }
    }
}

// fill CSR from key: int LDS slot counters seeded from per-chunk base (50 KB fits at RANGES=4)
__global__ __launch_bounds__(256) void k_fill2(const unsigned int* __restrict__ key,
                                               const int* __restrict__ base, int* __restrict__ col_src,
                                               int E, int N, int C, int RS, int L) {
    __shared__ int cnt[RSMAX];
    int r = blockIdx.x / C;
    int c = blockIdx.x % C;
    int r0 = r * RS;
    int r1 = min(r0 + RS, N);
    int nb = r1 - r0;
    const int* bc = base + (size_t)c * N;
    for (int i = threadIdx.x; i < nb; i += 256) cnt[i] = bc[r0 + i];
    __syncthreads();
    int e0 = c * L, e1 = min(e0 + L, E);
    for (int e = e0 + threadIdx.x * 4; e < e1; e += 1024) {
        if (e + 3 < e1) {
            uint4 k4 = *(const uint4*)&key[e];
            #pragma unroll
            for (int j = 0; j < 4; ++j) {
                unsigned int kk = (j == 0) ? k4.x : (j == 1) ? k4.y : (j == 2) ? k4.z : k4.w;
                int s = (int)(kk & 0xFFFFu);
                int d = (int)(kk >> 16);
                if (d >= r0 && d < r1) { int o = atomicAdd(&cnt[d - r0], 1); col_src[o] = s; }
            }
        } else {
            for (int j = 0; j < 4 && e + j < e1; ++j) {
                unsigned int kk = key[e + j];
                int s = (int)(kk & 0xFFFFu);
                int d = (int)(kk >> 16);
                if (d >= r0 && d < r1) { int o = atomicAdd(&cnt[d - r0], 1); col_src[o] = s; }
            }
        }
    }
}

__device__ inline void acc_row(float* acc, uint4 u) {
    const __half2* h = (const __half2*)&u;
    #pragma unroll
    for (int i = 0; i < 4; ++i) {
        float2 f = __half22float2(h[i]);
        acc[2 * i] += f.x;
        acc[2 * i + 1] += f.y;
    }
}

// pull-mode aggregation: 16 lanes/node, uint4 per lane, idx prefetch, plain loads.
__global__ __launch_bounds__(256, 8) void k_agg(const uint4* __restrict__ Xin, const float* __restrict__ norm_in,
                                                const int* __restrict__ row_ptr, const int* __restrict__ col_src,
                                                uint4* __restrict__ Yh, int N) {
    int t = threadIdx.x;
    int l16 = t & 15;
    int n = blockIdx.x * 16 + (t >> 4);
    if (n >= N) return;
    int beg = row_ptr[n], end = row_ptr[n + 1];
    float acc[8] = {};
    int k = beg;
    bool have = (k + 3 < end);
    int4 s = make_int4(0, 0, 0, 0);
    if (have) s = *(const int4*)&col_src[k];
    while (have) {
        int kn = k + 4;
        bool haven = (kn + 3 < end);
        int4 sn = s;
        if (haven) sn = *(const int4*)&col_src[kn];
        uint4 u0 = Xin[(size_t)s.x * 16 + l16];
        uint4 u1 = Xin[(size_t)s.y * 16 + l16];
        uint4 u2 = Xin[(size_t)s.z * 16 + l16];
        uint4 u3 = Xin[(size_t)s.w * 16 + l16];
        acc_row(acc, u0);
        acc_row(acc, u1);
        acc_row(acc, u2);
        acc_row(acc, u3);
        s = sn; k = kn; have = haven;
    }
    for (; k < end; ++k) {
        uint4 u = Xin[(size_t)col_src[k] * 16 + l16];
        acc_row(acc, u);
    }
    float ni = norm_in[n];
    #pragma unroll
    for (int i = 0; i < 8; ++i) acc[i] *= ni;
    __half2 hp[4];
    #pragma unroll
    for (int i = 0; i < 4; ++i) hp[i] = __floats2half2_rn(acc[2 * i], acc[2 * i + 1]);
    Yh[(size_t)n * 16 + l16] = *(uint4*)hp;
}

// MFMA GEMM, 128-node tile: z = relu(Yh[n] @ W + b); outh = half(z*sc) or outf = z.
// wave handles rows m0..m0+31 as two 16-row sub-tiles.
__global__ __launch_bounds__(256) void k_mm_mfma(const __half* __restrict__ Yh, const __half* __restrict__ Wt,
                                                 const float* __restrict__ bl, const float* __restrict__ scale,
                                                 float* __restrict__ outf, __half* __restrict__ outh, int N) {
    __shared__ _Float16 Ah[128 * 136];
    __shared__ _Float16 Bt[128 * 136];
    int tid = threadIdx.x;
    int n0 = blockIdx.x * 128;

    for (int q = tid; q < 2048; q += 256) {
        int rr = q >> 4, cc = q & 15;
        int node = n0 + rr;
        float4 v = make_float4(0.f, 0.f, 0.f, 0.f);
        if (node < N) v = *(const float4*)&Yh[(size_t)node * 128 + cc * 8];
        *(float4*)&Ah[rr * 136 + cc * 8] = v;
        *(float4*)&Bt[rr * 136 + cc * 8] = *(const float4*)&Wt[(size_t)rr * 128 + cc * 8];
    }
    __syncthreads();

    int wave = tid >> 6;
    int lane = tid & 63;
    int quad = lane >> 4;
    int mrow = lane & 15;
    int m0 = wave * 32;

    half8 af[2][4];
    #pragma unroll
    for (int sub = 0; sub < 2; ++sub)
        #pragma unroll
        for (int kc = 0; kc < 4; ++kc)
            af[sub][kc] = *(const half8*)&Ah[(m0 + sub * 16 + mrow) * 136 + kc * 32 + quad * 8];

    floatx4 acc[2][8];
    #pragma unroll
    for (int sub = 0; sub < 2; ++sub)
        #pragma unroll
        for (int ct = 0; ct < 8; ++ct) acc[sub][ct] = (floatx4){0.f, 0.f, 0.f, 0.f};

    #pragma unroll
    for (int ct = 0; ct < 8; ++ct) {
        #pragma unroll
        for (int kc = 0; kc < 4; ++kc) {
            half8 bf = *(const half8*)&Bt[(ct * 16 + mrow) * 136 + kc * 32 + quad * 8];
            acc[0][ct] = __builtin_amdgcn_mfma_f32_16x16x32_f16(af[0][kc], bf, acc[0][ct], 0, 0, 0);
            acc[1][ct] = __builtin_amdgcn_mfma_f32_16x16x32_f16(af[1][kc], bf, acc[1][ct], 0, 0, 0);
        }
    }

    #pragma unroll
    for (int sub = 0; sub < 2; ++sub) {
        float sc[4];
        #pragma unroll
        for (int r = 0; r < 4; ++r) {
            int node = n0 + m0 + sub * 16 + quad * 4 + r;
            sc[r] = (scale && node < N) ? scale[node] : 1.0f;
        }
        #pragma unroll
        for (int ct = 0; ct < 8; ++ct) {
            int col = ct * 16 + mrow;
            float bias = bl[col];
            #pragma unroll
            for (int r = 0; r < 4; ++r) {
                int node = n0 + m0 + sub * 16 + quad * 4 + r;
                if (node < N) {
                    float val = fmaxf(acc[sub][ct][r] + bias, 0.f);
                    if (outh) outh[(size_t)node * 128 + col] = __float2half(val * sc[r]);
                    else outf[(size_t)node * 128 + col] = val;
                }
            }
        }
    }
}

// pooled mean readout from half F
__global__ __launch_bounds__(256) void k_pool(const __half2* __restrict__ Fh, const int* __restrict__ g_start,
                                              float* __restrict__ out) {
    __shared__ float2 red[4][64];
    int g = blockIdx.x;
    int t = threadIdx.x;
    int cp = t & 63;
    int nl = t >> 6;
    int beg = g_start[g], end = g_start[g + 1];
    float2 acc = make_float2(0.f, 0.f);
    for (int n = beg + nl; n < end; n += 4) {
        float2 f = __half22float2(Fh[(size_t)n * 64 + cp]);
        acc.x += f.x;
        acc.y += f.y;
    }
    red[nl][cp] = acc;
    __syncthreads();
    if (nl == 0) {
        float2 a0 = red[0][cp], a1 = red[1][cp], a2 = red[2][cp], a3 = red[3][cp];
        float cnt = fmaxf((float)(end - beg), 1.0f);
        float2 o;
        o.x = (a0.x + a1.x + a2.x + a3.x) / cnt;
        o.y = (a0.y + a1.y + a2.y + a3.y) / cnt;
        *(float2*)&out[(size_t)g * DD + cp * 2] = o;
    }
}

extern "C" void kernel_launch(void* const* d_in, const int* in_sizes, int n_in,
                              void* d_out, int out_size, void* d_ws, size_t ws_size,
                              hipStream_t stream) {
    const float* feats = (const float*)d_in[0];
    const float* W = (const float*)d_in[1];
    const float* b = (const float*)d_in[2];
    const int* src = (const int*)d_in[3];
    const int* dst = (const int*)d_in[4];
    const int* gid = (const int*)d_in[5];
    float* out = (float*)d_out;
    const int N = in_sizes[0] / DD;  // 50000
    const int E = in_sizes[3];       // 800000

    const int C = NCHUNK;                        // 64
    const int RS = (N + RANGES - 1) / RANGES;    // 12500 <= RSMAX
    const int L = (((E + C - 1) / C) + 3) & ~3;  // 12500

    char* ws = (char*)d_ws;
    size_t off = 0;
    auto take = [&](size_t bytes) {
        char* p = ws + off;
        off = (off + bytes + 255) & ~(size_t)255;
        return p;
    };
    float* norm_out = (float*)take((size_t)N * 4);
    float* norm_in  = (float*)take((size_t)N * 4);
    int*   deg_in   = (int*)take((size_t)N * 4);
    int*   row_ptr  = (int*)take((size_t)(N + 1) * 4);
    int*   col_src  = (int*)take((size_t)E * 4);
    int*   g_start  = (int*)take((size_t)(GG + 1) * 4);
    int*   bsum     = (int*)take((size_t)1024 * 4);
    unsigned int* key = (unsigned int*)take((size_t)E * 4);
    __half* Wth     = (__half*)take((size_t)3 * 16384 * 2);
    uint4* Xh       = (uint4*)take((size_t)N * DD * 2);   // half features
    uint4* Yh       = (uint4*)take((size_t)N * DD * 2);   // half agg output
    // union: pk + fbase during preprocessing; Fh (half final layer) afterwards
    size_t chunk_arr = ((size_t)C * N * 4 + 255) & ~(size_t)255;   // 12.8 MB
    size_t uni_bytes = 2 * chunk_arr;
    size_t fh_bytes = (size_t)N * DD * 2;
    char* uni = take(uni_bytes > fh_bytes ? uni_bytes : fh_bytes);
    unsigned int* pk = (unsigned int*)uni;
    int* fbase = (int*)(uni + chunk_arr);
    __half* Fh = (__half*)uni;  // alias: used only after preprocessing completes

    const int nblk = (N + 255) / 256;  // 196 reduce/scan chunks
    const int mgrid_misc = 195 + (N * 32 + 255) / 256;

    k_key<<<(E + 1023) / 1024, 256, 0, stream>>>(src, dst, key, E);
    k_hist2<<<RANGES * C, 256, 0, stream>>>(key, pk, E, N, C, RS, L);
    k_reduce<<<nblk, 256, 0, stream>>>(pk, norm_out, norm_in, deg_in, bsum, N, C);
    k_misc<<<mgrid_misc, 256, 0, stream>>>(bsum, nblk, row_ptr, N, gid, g_start, GG,
                                           W, Wth, feats, norm_out, (uint2*)Xh);
    k_scan_cb<<<nblk, 256, 0, stream>>>(deg_in, bsum, pk, row_ptr, fbase, N, C);
    k_fill2<<<RANGES * C, 256, 0, stream>>>(key, fbase, col_src, E, N, C, RS, L);

    const int agrid = (N + 15) / 16;
    const int mgrid = (N + 127) / 128;
    for (int l = 0; l < 3; ++l) {
        k_agg<<<agrid, 256, 0, stream>>>(Xh, norm_in, row_ptr, col_src, Yh, N);
        const __half* Wtl = Wth + (size_t)l * 16384;
        const float* bl = b + (size_t)l * DD;
        if (l < 2)
            k_mm_mfma<<<mgrid, 256, 0, stream>>>((const __half*)Yh, Wtl, bl, norm_out,
                                                 nullptr, (__half*)Xh, N);
        else
            k_mm_mfma<<<mgrid, 256, 0, stream>>>((const __half*)Yh, Wtl, bl, nullptr,
                                                 nullptr, Fh, N);
    }
    k_pool<<<GG, 256, 0, stream>>>((const __half2*)Fh, g_start, out);
}